// Round 9
// baseline (61.597 us; speedup 1.0000x reference)
//
#include <hip/hip_runtime.h>
#include <hip/hip_bf16.h>

// Lovasz-Softmax loss, sort-free histogram formulation.
//
// Math: per class, sorting errors descending and accumulating grad*e is
// invariant to permutation within equal-error runs (jaccard value depends only
// on cumulative (i,k)). Quantizing e in [0,1] into NB linear bins gives exact
// cumulative counts at bin boundaries; bin-center representative bounds total
// error by 1/(2*NB) = 3.9e-3 at NB=128, 4.9x under the 1.9e-2 threshold.
//
// R9: hist is at the compulsory-byte floor (318MB pred through ~7TB/s
// L3/HBM mixed path, ~48us); all that's left is the tail. NB 256->128 halves
// LDS zero/writeout, scratch round-trip (10->5MB), reduce, and perclass.

#define NCLS 19
#define NB 128
#define HWSZ 262144          // 512*512
#define NPIX 2097152         // 8*512*512
#define HISTW (NCLS * NB)    // 2432 words per histogram copy
#define RED_SPLIT 32
#define NBLK 512

__global__ __launch_bounds__(256) void lovasz_hist_kernel(
    const float* __restrict__ pred, const int* __restrict__ tgt,
    unsigned int* __restrict__ gh)
{
    __shared__ unsigned int lh[HISTW];   // packed: low16 = count, high16 = target count
    for (int j = threadIdx.x; j < HISTW; j += 256) lh[j] = 0u;
    __syncthreads();

    const int stride = gridDim.x * 256;
    // 4 pixels per iteration (float4 / int4 loads)
    for (int g = blockIdx.x * 256 + threadIdx.x; g < (NPIX >> 2); g += stride) {
        const int idx = g << 2;
        const int b  = idx >> 18;          // / (512*512)
        const int hw = idx & (HWSZ - 1);   // multiple of 4; 16B-aligned
        const float* base = pred + ((size_t)b * NCLS) * HWSZ + hw;

        const int4 t4 = *(const int4*)(tgt + idx);

        float x0[NCLS], x1[NCLS], x2[NCLS], x3[NCLS];
        #pragma unroll
        for (int c = 0; c < NCLS; ++c) {
            const float4 v = *(const float4*)(base + (size_t)c * HWSZ);
            x0[c] = v.x; x1[c] = v.y; x2[c] = v.z; x3[c] = v.w;
        }

        // softmax without max-subtraction: logits are O(few), exp safe in fp32
        float s0 = 0.f, s1 = 0.f, s2 = 0.f, s3 = 0.f;
        #pragma unroll
        for (int c = 0; c < NCLS; ++c) {
            x0[c] = __expf(x0[c]); s0 += x0[c];
            x1[c] = __expf(x1[c]); s1 += x1[c];
            x2[c] = __expf(x2[c]); s2 += x2[c];
            x3[c] = __expf(x3[c]); s3 += x3[c];
        }
        const float inv0 = 1.f / s0, inv1 = 1.f / s1;
        const float inv2 = 1.f / s2, inv3 = 1.f / s3;

        #pragma unroll
        for (int c = 0; c < NCLS; ++c) {
            {
                const float p = x0[c] * inv0;
                const bool ist = (c == t4.x);
                const float e = ist ? (1.f - p) : p;
                int q = (int)(e * (float)NB);
                q = q < 0 ? 0 : (q > NB - 1 ? NB - 1 : q);
                atomicAdd(&lh[c * NB + q], ist ? 0x10001u : 1u);
            }
            {
                const float p = x1[c] * inv1;
                const bool ist = (c == t4.y);
                const float e = ist ? (1.f - p) : p;
                int q = (int)(e * (float)NB);
                q = q < 0 ? 0 : (q > NB - 1 ? NB - 1 : q);
                atomicAdd(&lh[c * NB + q], ist ? 0x10001u : 1u);
            }
            {
                const float p = x2[c] * inv2;
                const bool ist = (c == t4.z);
                const float e = ist ? (1.f - p) : p;
                int q = (int)(e * (float)NB);
                q = q < 0 ? 0 : (q > NB - 1 ? NB - 1 : q);
                atomicAdd(&lh[c * NB + q], ist ? 0x10001u : 1u);
            }
            {
                const float p = x3[c] * inv3;
                const bool ist = (c == t4.w);
                const float e = ist ? (1.f - p) : p;
                int q = (int)(e * (float)NB);
                q = q < 0 ? 0 : (q > NB - 1 ? NB - 1 : q);
                atomicAdd(&lh[c * NB + q], ist ? 0x10001u : 1u);
            }
        }
    }
    __syncthreads();

    unsigned int* dst = gh + (size_t)blockIdx.x * HISTW;
    for (int j = threadIdx.x; j < HISTW; j += 256) dst[j] = lh[j];
}

// Stage A: grid (HISTW/128, RED_SPLIT), block 128. Block (jc, k) sums
// histograms [k*nper, (k+1)*nper) into unpacked partials.
__global__ __launch_bounds__(128) void lovasz_reduce_kernel(
    const unsigned int* __restrict__ gh,
    unsigned int* __restrict__ cntp, unsigned int* __restrict__ tcntp, int nblk)
{
    const int j = blockIdx.x * 128 + threadIdx.x;   // < HISTW (grid sized exactly)
    const int k = blockIdx.y;
    const int nper = (nblk + RED_SPLIT - 1) / RED_SPLIT;
    const int b0 = k * nper;
    int b1 = b0 + nper; if (b1 > nblk) b1 = nblk;

    unsigned int cs = 0, ts = 0;
    for (int b = b0; b < b1; ++b) {
        const unsigned int w = gh[(size_t)b * HISTW + j];
        cs += w & 0xFFFFu;
        ts += w >> 16;
    }
    cntp[(size_t)k * HISTW + j] = cs;
    tcntp[(size_t)k * HISTW + j] = ts;
}

__global__ __launch_bounds__(NB) void lovasz_perclass_kernel(
    const unsigned int* __restrict__ cntp, const unsigned int* __restrict__ tcntp,
    float* __restrict__ pc, int* __restrict__ present)
{
    const int c = blockIdx.x;       // class
    const int d = threadIdx.x;      // 0..NB-1, descending-bin position
    const int bin = (NB - 1) - d;
    const int col = c * NB + bin;

    __shared__ unsigned int sI[NB];
    __shared__ unsigned int sK[NB];
    __shared__ float acc;

    unsigned int n = 0, m = 0;
    #pragma unroll
    for (int k = 0; k < RED_SPLIT; ++k) {
        n += cntp[(size_t)k * HISTW + col];
        m += tcntp[(size_t)k * HISTW + col];
    }
    sI[d] = n;
    sK[d] = m;
    if (d == 0) acc = 0.f;
    __syncthreads();

    // Hillis-Steele inclusive scan over descending-bin order
    for (int off = 1; off < NB; off <<= 1) {
        unsigned int vI = 0, vK = 0;
        if (d >= off) { vI = sI[d - off]; vK = sK[d - off]; }
        __syncthreads();
        sI[d] += vI;
        sK[d] += vK;
        __syncthreads();
    }

    const unsigned int I = sI[d];
    const unsigned int K = sK[d];
    const unsigned int G = sK[NB - 1];   // total target pixels of this class

    float contrib = 0.f;
    if (n > 0u && G > 0u) {
        const float Jc = 1.f - (float)(G - K) / (float)(G + I - K);
        const unsigned int Ip = I - n, Kp = K - m;
        const float Jp = 1.f - (float)(G - Kp) / (float)(G + Ip - Kp); // denom >= G > 0
        const float v = ((float)bin + 0.5f) * (1.f / (float)NB);
        contrib = v * (Jc - Jp);
    }
    atomicAdd(&acc, contrib);
    __syncthreads();
    if (d == 0) {
        pc[c] = acc;
        present[c] = (G > 0u) ? 1 : 0;
    }
}

__global__ void lovasz_final_kernel(const float* __restrict__ pc,
                                    const int* __restrict__ present,
                                    float* __restrict__ out)
{
    if (blockIdx.x == 0 && threadIdx.x == 0) {
        float s = 0.f;
        int np = 0;
        for (int c = 0; c < NCLS; ++c) {
            if (present[c]) { s += pc[c]; ++np; }
        }
        out[0] = s / (float)(np > 0 ? np : 1);
    }
}

extern "C" void kernel_launch(void* const* d_in, const int* in_sizes, int n_in,
                              void* d_out, int out_size, void* d_ws, size_t ws_size,
                              hipStream_t stream)
{
    const float* pred = (const float*)d_in[0];
    const int* tgt    = (const int*)d_in[1];
    float* out        = (float*)d_out;

    unsigned int* ws = (unsigned int*)d_ws;
    // ws layout (u32 word offsets):
    //   [0, 77824)          cntp   (RED_SPLIT * HISTW)
    //   [77824, 155648)     tcntp  (RED_SPLIT * HISTW)
    //   [155648, 155667)    pc (float)
    //   [155667, 155686)    present (int)
    //   [163840, ...)       per-block histograms (nblk * HISTW u32)
    unsigned int* cntp  = ws;
    unsigned int* tcntp = ws + RED_SPLIT * HISTW;
    float* pc           = (float*)(ws + 2 * RED_SPLIT * HISTW);
    int* present        = (int*)(ws + 2 * RED_SPLIT * HISTW + NCLS);
    unsigned int* gh    = ws + 163840;

    const size_t reserved = 163840u * 4u;
    const size_t hbytes = (size_t)HISTW * 4u;
    int nblk = NBLK;
    const size_t avail = (ws_size > reserved) ? (ws_size - reserved) : 0;
    if ((size_t)nblk * hbytes > avail) nblk = (int)(avail / hbytes);
    if (nblk < 32) nblk = 32;   // keep 16-bit packed block-local counts safe

    hipLaunchKernelGGL(lovasz_hist_kernel, dim3(nblk), dim3(256), 0, stream,
                       pred, tgt, gh);
    hipLaunchKernelGGL(lovasz_reduce_kernel, dim3(HISTW / 128, RED_SPLIT), dim3(128), 0, stream,
                       gh, cntp, tcntp, nblk);
    hipLaunchKernelGGL(lovasz_perclass_kernel, dim3(NCLS), dim3(NB), 0, stream,
                       cntp, tcntp, pc, present);
    hipLaunchKernelGGL(lovasz_final_kernel, dim3(1), dim3(64), 0, stream,
                       pc, present, out);
}

// Round 10
// 59.786 us; speedup vs baseline: 1.0303x; 1.0303x over previous
//
#include <hip/hip_runtime.h>
#include <hip/hip_bf16.h>

// Lovasz-Softmax loss, sort-free histogram formulation.
//
// Math: per class, sorting errors descending and accumulating grad*e is
// invariant to permutation within equal-error runs (jaccard value depends only
// on cumulative (i,k)). Quantizing e in [0,1] into NB linear bins gives exact
// cumulative counts at bin boundaries; bin-center representative bounds total
// error by 1/(2*NB) = 3.9e-3 at NB=128, 4.9x under the 1.9e-2 threshold.
//
// R10: R9 (NB=128, one copy) regressed vs R8 (NB=256) by +4.8us with LESS
// traffic -> hist is partly LDS-atomic same-address serialization bound;
// halving bins doubled per-bin multiplicity. Fix: NB=128 with TWO LDS copies
// split by lane parity: atomic-target spread = R8 (4864 words), within-wave
// same-address multiplicity halved vs R9, tail/scratch stays at R9's halved
// size (5MB). Packed merge at writeout is carry-safe (<=4096+4096 < 65536).

#define NCLS 19
#define NB 128
#define HWSZ 262144          // 512*512
#define NPIX 2097152         // 8*512*512
#define HISTW (NCLS * NB)    // 2432 words per histogram copy
#define RED_SPLIT 32
#define NBLK 512

__global__ __launch_bounds__(256) void lovasz_hist_kernel(
    const float* __restrict__ pred, const int* __restrict__ tgt,
    unsigned int* __restrict__ gh)
{
    __shared__ unsigned int lh[2][HISTW];   // packed: low16 = count, high16 = target count
    for (int j = threadIdx.x; j < 2 * HISTW; j += 256) lh[0][j] = 0u;
    __syncthreads();

    unsigned int* myh = lh[threadIdx.x & 1];

    const int stride = gridDim.x * 256;
    // 4 pixels per iteration (float4 / int4 loads)
    for (int g = blockIdx.x * 256 + threadIdx.x; g < (NPIX >> 2); g += stride) {
        const int idx = g << 2;
        const int b  = idx >> 18;          // / (512*512)
        const int hw = idx & (HWSZ - 1);   // multiple of 4; 16B-aligned
        const float* base = pred + ((size_t)b * NCLS) * HWSZ + hw;

        const int4 t4 = *(const int4*)(tgt + idx);

        float x0[NCLS], x1[NCLS], x2[NCLS], x3[NCLS];
        #pragma unroll
        for (int c = 0; c < NCLS; ++c) {
            const float4 v = *(const float4*)(base + (size_t)c * HWSZ);
            x0[c] = v.x; x1[c] = v.y; x2[c] = v.z; x3[c] = v.w;
        }

        // softmax without max-subtraction: logits are O(few), exp safe in fp32
        float s0 = 0.f, s1 = 0.f, s2 = 0.f, s3 = 0.f;
        #pragma unroll
        for (int c = 0; c < NCLS; ++c) {
            x0[c] = __expf(x0[c]); s0 += x0[c];
            x1[c] = __expf(x1[c]); s1 += x1[c];
            x2[c] = __expf(x2[c]); s2 += x2[c];
            x3[c] = __expf(x3[c]); s3 += x3[c];
        }
        const float inv0 = 1.f / s0, inv1 = 1.f / s1;
        const float inv2 = 1.f / s2, inv3 = 1.f / s3;

        #pragma unroll
        for (int c = 0; c < NCLS; ++c) {
            {
                const float p = x0[c] * inv0;
                const bool ist = (c == t4.x);
                const float e = ist ? (1.f - p) : p;
                int q = (int)(e * (float)NB);
                q = q < 0 ? 0 : (q > NB - 1 ? NB - 1 : q);
                atomicAdd(&myh[c * NB + q], ist ? 0x10001u : 1u);
            }
            {
                const float p = x1[c] * inv1;
                const bool ist = (c == t4.y);
                const float e = ist ? (1.f - p) : p;
                int q = (int)(e * (float)NB);
                q = q < 0 ? 0 : (q > NB - 1 ? NB - 1 : q);
                atomicAdd(&myh[c * NB + q], ist ? 0x10001u : 1u);
            }
            {
                const float p = x2[c] * inv2;
                const bool ist = (c == t4.z);
                const float e = ist ? (1.f - p) : p;
                int q = (int)(e * (float)NB);
                q = q < 0 ? 0 : (q > NB - 1 ? NB - 1 : q);
                atomicAdd(&myh[c * NB + q], ist ? 0x10001u : 1u);
            }
            {
                const float p = x3[c] * inv3;
                const bool ist = (c == t4.w);
                const float e = ist ? (1.f - p) : p;
                int q = (int)(e * (float)NB);
                q = q < 0 ? 0 : (q > NB - 1 ? NB - 1 : q);
                atomicAdd(&myh[c * NB + q], ist ? 0x10001u : 1u);
            }
        }
    }
    __syncthreads();

    // Merge the two parity copies (packed add is carry-safe: per-copy bin
    // counts <= 4096, sum < 65536) and write one histogram per block.
    unsigned int* dst = gh + (size_t)blockIdx.x * HISTW;
    for (int j = threadIdx.x; j < HISTW; j += 256)
        dst[j] = lh[0][j] + lh[1][j];
}

// Stage A: grid (HISTW/128, RED_SPLIT), block 128. Block (jc, k) sums
// histograms [k*nper, (k+1)*nper) into unpacked partials.
__global__ __launch_bounds__(128) void lovasz_reduce_kernel(
    const unsigned int* __restrict__ gh,
    unsigned int* __restrict__ cntp, unsigned int* __restrict__ tcntp, int nblk)
{
    const int j = blockIdx.x * 128 + threadIdx.x;   // < HISTW (grid sized exactly)
    const int k = blockIdx.y;
    const int nper = (nblk + RED_SPLIT - 1) / RED_SPLIT;
    const int b0 = k * nper;
    int b1 = b0 + nper; if (b1 > nblk) b1 = nblk;

    unsigned int cs = 0, ts = 0;
    for (int b = b0; b < b1; ++b) {
        const unsigned int w = gh[(size_t)b * HISTW + j];
        cs += w & 0xFFFFu;
        ts += w >> 16;
    }
    cntp[(size_t)k * HISTW + j] = cs;
    tcntp[(size_t)k * HISTW + j] = ts;
}

__global__ __launch_bounds__(NB) void lovasz_perclass_kernel(
    const unsigned int* __restrict__ cntp, const unsigned int* __restrict__ tcntp,
    float* __restrict__ pc, int* __restrict__ present)
{
    const int c = blockIdx.x;       // class
    const int d = threadIdx.x;      // 0..NB-1, descending-bin position
    const int bin = (NB - 1) - d;
    const int col = c * NB + bin;

    __shared__ unsigned int sI[NB];
    __shared__ unsigned int sK[NB];
    __shared__ float acc;

    unsigned int n = 0, m = 0;
    #pragma unroll
    for (int k = 0; k < RED_SPLIT; ++k) {
        n += cntp[(size_t)k * HISTW + col];
        m += tcntp[(size_t)k * HISTW + col];
    }
    sI[d] = n;
    sK[d] = m;
    if (d == 0) acc = 0.f;
    __syncthreads();

    // Hillis-Steele inclusive scan over descending-bin order
    for (int off = 1; off < NB; off <<= 1) {
        unsigned int vI = 0, vK = 0;
        if (d >= off) { vI = sI[d - off]; vK = sK[d - off]; }
        __syncthreads();
        sI[d] += vI;
        sK[d] += vK;
        __syncthreads();
    }

    const unsigned int I = sI[d];
    const unsigned int K = sK[d];
    const unsigned int G = sK[NB - 1];   // total target pixels of this class

    float contrib = 0.f;
    if (n > 0u && G > 0u) {
        const float Jc = 1.f - (float)(G - K) / (float)(G + I - K);
        const unsigned int Ip = I - n, Kp = K - m;
        const float Jp = 1.f - (float)(G - Kp) / (float)(G + Ip - Kp); // denom >= G > 0
        const float v = ((float)bin + 0.5f) * (1.f / (float)NB);
        contrib = v * (Jc - Jp);
    }
    atomicAdd(&acc, contrib);
    __syncthreads();
    if (d == 0) {
        pc[c] = acc;
        present[c] = (G > 0u) ? 1 : 0;
    }
}

__global__ void lovasz_final_kernel(const float* __restrict__ pc,
                                    const int* __restrict__ present,
                                    float* __restrict__ out)
{
    if (blockIdx.x == 0 && threadIdx.x == 0) {
        float s = 0.f;
        int np = 0;
        for (int c = 0; c < NCLS; ++c) {
            if (present[c]) { s += pc[c]; ++np; }
        }
        out[0] = s / (float)(np > 0 ? np : 1);
    }
}

extern "C" void kernel_launch(void* const* d_in, const int* in_sizes, int n_in,
                              void* d_out, int out_size, void* d_ws, size_t ws_size,
                              hipStream_t stream)
{
    const float* pred = (const float*)d_in[0];
    const int* tgt    = (const int*)d_in[1];
    float* out        = (float*)d_out;

    unsigned int* ws = (unsigned int*)d_ws;
    // ws layout (u32 word offsets):
    //   [0, 77824)          cntp   (RED_SPLIT * HISTW)
    //   [77824, 155648)     tcntp  (RED_SPLIT * HISTW)
    //   [155648, 155667)    pc (float)
    //   [155667, 155686)    present (int)
    //   [163840, ...)       per-block histograms (nblk * HISTW u32)
    unsigned int* cntp  = ws;
    unsigned int* tcntp = ws + RED_SPLIT * HISTW;
    float* pc           = (float*)(ws + 2 * RED_SPLIT * HISTW);
    int* present        = (int*)(ws + 2 * RED_SPLIT * HISTW + NCLS);
    unsigned int* gh    = ws + 163840;

    const size_t reserved = 163840u * 4u;
    const size_t hbytes = (size_t)HISTW * 4u;
    int nblk = NBLK;
    const size_t avail = (ws_size > reserved) ? (ws_size - reserved) : 0;
    if ((size_t)nblk * hbytes > avail) nblk = (int)(avail / hbytes);
    if (nblk < 32) nblk = 32;   // keep 16-bit packed block-local counts safe

    hipLaunchKernelGGL(lovasz_hist_kernel, dim3(nblk), dim3(256), 0, stream,
                       pred, tgt, gh);
    hipLaunchKernelGGL(lovasz_reduce_kernel, dim3(HISTW / 128, RED_SPLIT), dim3(128), 0, stream,
                       gh, cntp, tcntp, nblk);
    hipLaunchKernelGGL(lovasz_perclass_kernel, dim3(NCLS), dim3(NB), 0, stream,
                       cntp, tcntp, pc, present);
    hipLaunchKernelGGL(lovasz_final_kernel, dim3(1), dim3(64), 0, stream,
                       pc, present, out);
}

// Round 11
// 57.041 us; speedup vs baseline: 1.0799x; 1.0481x over previous
//
#include <hip/hip_runtime.h>
#include <hip/hip_bf16.h>

// Lovasz-Softmax loss, sort-free histogram formulation.
//
// Math: per class, sorting errors descending and accumulating grad*e is
// invariant to permutation within equal-error runs (jaccard value depends only
// on cumulative (i,k)). Quantizing e in [0,1] into NB linear bins gives exact
// cumulative counts at bin boundaries; bin-center representative bounds total
// error by 1/(2*NB) = 2.0e-3 at NB=256, 9.7x under the 1.9e-2 threshold.
//
// R11: hist reverted to R8 exactly (best measured: NB=256 single LDS copy,
// ~6.9 TB/s effective = streaming floor). Tail-only changes: NBLK 512->256
// (scratch round-trip 20->10 MB total), perclass+final fused via last-block
// ticket with fixed-point (x2^24) u64 accumulation — integer atomics, order-
// invariant, deterministic. Counters zeroed by reduce (stream-ordered).

#define NCLS 19
#define NB 256
#define HWSZ 262144          // 512*512
#define NPIX 2097152         // 8*512*512
#define HISTW (NCLS * NB)    // 4864 words per histogram copy
#define RED_SPLIT 32
#define NBLK 256

__global__ __launch_bounds__(256) void lovasz_hist_kernel(
    const float* __restrict__ pred, const int* __restrict__ tgt,
    unsigned int* __restrict__ gh)
{
    __shared__ unsigned int lh[HISTW];   // packed: low16 = count, high16 = target count
    for (int j = threadIdx.x; j < HISTW; j += 256) lh[j] = 0u;
    __syncthreads();

    const int stride = gridDim.x * 256;
    // 4 pixels per iteration (float4 / int4 loads)
    for (int g = blockIdx.x * 256 + threadIdx.x; g < (NPIX >> 2); g += stride) {
        const int idx = g << 2;
        const int b  = idx >> 18;          // / (512*512)
        const int hw = idx & (HWSZ - 1);   // multiple of 4; 16B-aligned
        const float* base = pred + ((size_t)b * NCLS) * HWSZ + hw;

        const int4 t4 = *(const int4*)(tgt + idx);

        float x0[NCLS], x1[NCLS], x2[NCLS], x3[NCLS];
        #pragma unroll
        for (int c = 0; c < NCLS; ++c) {
            const float4 v = *(const float4*)(base + (size_t)c * HWSZ);
            x0[c] = v.x; x1[c] = v.y; x2[c] = v.z; x3[c] = v.w;
        }

        // softmax without max-subtraction: logits are O(few), exp safe in fp32
        float s0 = 0.f, s1 = 0.f, s2 = 0.f, s3 = 0.f;
        #pragma unroll
        for (int c = 0; c < NCLS; ++c) {
            x0[c] = __expf(x0[c]); s0 += x0[c];
            x1[c] = __expf(x1[c]); s1 += x1[c];
            x2[c] = __expf(x2[c]); s2 += x2[c];
            x3[c] = __expf(x3[c]); s3 += x3[c];
        }
        const float inv0 = 1.f / s0, inv1 = 1.f / s1;
        const float inv2 = 1.f / s2, inv3 = 1.f / s3;

        #pragma unroll
        for (int c = 0; c < NCLS; ++c) {
            {
                const float p = x0[c] * inv0;
                const bool ist = (c == t4.x);
                const float e = ist ? (1.f - p) : p;
                int q = (int)(e * (float)NB);
                q = q < 0 ? 0 : (q > NB - 1 ? NB - 1 : q);
                atomicAdd(&lh[c * NB + q], ist ? 0x10001u : 1u);
            }
            {
                const float p = x1[c] * inv1;
                const bool ist = (c == t4.y);
                const float e = ist ? (1.f - p) : p;
                int q = (int)(e * (float)NB);
                q = q < 0 ? 0 : (q > NB - 1 ? NB - 1 : q);
                atomicAdd(&lh[c * NB + q], ist ? 0x10001u : 1u);
            }
            {
                const float p = x2[c] * inv2;
                const bool ist = (c == t4.z);
                const float e = ist ? (1.f - p) : p;
                int q = (int)(e * (float)NB);
                q = q < 0 ? 0 : (q > NB - 1 ? NB - 1 : q);
                atomicAdd(&lh[c * NB + q], ist ? 0x10001u : 1u);
            }
            {
                const float p = x3[c] * inv3;
                const bool ist = (c == t4.w);
                const float e = ist ? (1.f - p) : p;
                int q = (int)(e * (float)NB);
                q = q < 0 ? 0 : (q > NB - 1 ? NB - 1 : q);
                atomicAdd(&lh[c * NB + q], ist ? 0x10001u : 1u);
            }
        }
    }
    __syncthreads();

    unsigned int* dst = gh + (size_t)blockIdx.x * HISTW;
    for (int j = threadIdx.x; j < HISTW; j += 256) dst[j] = lh[j];
}

// Stage A: grid (HISTW/256, RED_SPLIT). Block (jc, k) sums histograms
// [k*nper, (k+1)*nper) into unpacked partials. Block (0,0) also zeroes the
// ticket/sum counters used by the fused perclass+final kernel.
__global__ __launch_bounds__(256) void lovasz_reduce_kernel(
    const unsigned int* __restrict__ gh,
    unsigned int* __restrict__ cntp, unsigned int* __restrict__ tcntp,
    unsigned int* __restrict__ ctr /* [0]=ticket [1]=npres, [2..3]=sum u64 */,
    int nblk)
{
    if (blockIdx.x == 0 && blockIdx.y == 0 && threadIdx.x == 0) {
        ctr[0] = 0u; ctr[1] = 0u; ctr[2] = 0u; ctr[3] = 0u;
    }
    const int j = blockIdx.x * 256 + threadIdx.x;   // < HISTW (grid sized exactly)
    const int k = blockIdx.y;
    const int nper = (nblk + RED_SPLIT - 1) / RED_SPLIT;
    const int b0 = k * nper;
    int b1 = b0 + nper; if (b1 > nblk) b1 = nblk;

    unsigned int cs = 0, ts = 0;
    for (int b = b0; b < b1; ++b) {
        const unsigned int w = gh[(size_t)b * HISTW + j];
        cs += w & 0xFFFFu;
        ts += w >> 16;
    }
    cntp[(size_t)k * HISTW + j] = cs;
    tcntp[(size_t)k * HISTW + j] = ts;
}

// Fused per-class Lovasz + final mean. 19 blocks; each accumulates its class
// contribution into a fixed-point u64 (x 2^24, order-invariant integer
// atomics -> deterministic); the last block (ticket) writes out[0].
__global__ __launch_bounds__(NB) void lovasz_perclass_final_kernel(
    const unsigned int* __restrict__ cntp, const unsigned int* __restrict__ tcntp,
    unsigned int* __restrict__ ctr, float* __restrict__ out)
{
    const int c = blockIdx.x;       // class
    const int d = threadIdx.x;      // 0..NB-1, descending-bin position
    const int bin = (NB - 1) - d;
    const int col = c * NB + bin;

    __shared__ unsigned int sI[NB];
    __shared__ unsigned int sK[NB];
    __shared__ float acc;

    unsigned int n = 0, m = 0;
    #pragma unroll
    for (int k = 0; k < RED_SPLIT; ++k) {
        n += cntp[(size_t)k * HISTW + col];
        m += tcntp[(size_t)k * HISTW + col];
    }
    sI[d] = n;
    sK[d] = m;
    if (d == 0) acc = 0.f;
    __syncthreads();

    // Hillis-Steele inclusive scan over descending-bin order
    for (int off = 1; off < NB; off <<= 1) {
        unsigned int vI = 0, vK = 0;
        if (d >= off) { vI = sI[d - off]; vK = sK[d - off]; }
        __syncthreads();
        sI[d] += vI;
        sK[d] += vK;
        __syncthreads();
    }

    const unsigned int I = sI[d];
    const unsigned int K = sK[d];
    const unsigned int G = sK[NB - 1];   // total target pixels of this class

    float contrib = 0.f;
    if (n > 0u && G > 0u) {
        const float Jc = 1.f - (float)(G - K) / (float)(G + I - K);
        const unsigned int Ip = I - n, Kp = K - m;
        const float Jp = 1.f - (float)(G - Kp) / (float)(G + Ip - Kp); // denom >= G > 0
        const float v = ((float)bin + 0.5f) * (1.f / (float)NB);
        contrib = v * (Jc - Jp);
    }
    atomicAdd(&acc, contrib);
    __syncthreads();

    if (d == 0) {
        if (G > 0u) {
            // per-class value in [0,1]; fixed-point 2^24, sum < 19*2^24 < 2^63
            const unsigned long long fx =
                (unsigned long long)((double)acc * 16777216.0 + 0.5);
            atomicAdd((unsigned long long*)(ctr + 2), fx);
            atomicAdd(&ctr[1], 1u);
        }
        __threadfence();
        const unsigned int t = atomicAdd(&ctr[0], 1u);
        if (t == NCLS - 1) {
            // last block: all contributions visible (atomics at device scope)
            const unsigned long long s = atomicAdd((unsigned long long*)(ctr + 2), 0ull);
            const unsigned int np = atomicAdd(&ctr[1], 0u);
            out[0] = (float)((double)s / 16777216.0 / (double)(np ? np : 1u));
        }
    }
}

extern "C" void kernel_launch(void* const* d_in, const int* in_sizes, int n_in,
                              void* d_out, int out_size, void* d_ws, size_t ws_size,
                              hipStream_t stream)
{
    const float* pred = (const float*)d_in[0];
    const int* tgt    = (const int*)d_in[1];
    float* out        = (float*)d_out;

    unsigned int* ws = (unsigned int*)d_ws;
    // ws layout (u32 word offsets):
    //   [0, 155648)         cntp   (RED_SPLIT * HISTW)
    //   [155648, 311296)    tcntp  (RED_SPLIT * HISTW)
    //   [311296, 311300)    ctr: ticket, npres, sum_fixed(u64, 8B-aligned)
    //   [327680, ...)       per-block histograms (nblk * HISTW u32)
    unsigned int* cntp  = ws;
    unsigned int* tcntp = ws + RED_SPLIT * HISTW;
    unsigned int* ctr   = ws + 2 * RED_SPLIT * HISTW;   // word 311296; *4 = 8B-aligned
    unsigned int* gh    = ws + 327680;

    const size_t reserved = 327680u * 4u;
    const size_t hbytes = (size_t)HISTW * 4u;
    int nblk = NBLK;
    const size_t avail = (ws_size > reserved) ? (ws_size - reserved) : 0;
    if ((size_t)nblk * hbytes > avail) nblk = (int)(avail / hbytes);
    if (nblk < 32) nblk = 32;   // keep 16-bit packed block-local counts safe

    hipLaunchKernelGGL(lovasz_hist_kernel, dim3(nblk), dim3(256), 0, stream,
                       pred, tgt, gh);
    hipLaunchKernelGGL(lovasz_reduce_kernel, dim3(HISTW / 256, RED_SPLIT), dim3(256), 0, stream,
                       gh, cntp, tcntp, ctr, nblk);
    hipLaunchKernelGGL(lovasz_perclass_final_kernel, dim3(NCLS), dim3(NB), 0, stream,
                       cntp, tcntp, ctr, out);
}